// Round 1
// baseline (396.019 us; speedup 1.0000x reference)
//
#include <hip/hip_runtime.h>
#include <hip/hip_bf16.h>

#define B 2
#define H 32
#define S 2048
#define D 128

typedef __bf16 bf16x8 __attribute__((ext_vector_type(8)));
typedef unsigned short u16x8_t;
typedef float f32x4 __attribute__((ext_vector_type(4)));

union F8 { unsigned short u[8]; bf16x8 b; };

__device__ __forceinline__ unsigned short f2bf(float f) {
    union { float f; unsigned int u; } a; a.f = f;
    unsigned int u = a.u;
    unsigned int r = (u + 0x7fffu + ((u >> 16) & 1u)) >> 16;  // RNE
    return (unsigned short)r;
}

static constexpr float INV_SQRT_D = 0.08838834764831845f; // 1/sqrt(128)
static constexpr int NROWS = B * H * S; // 131072

// ---------------- quantize K: row-major bf16 codes + per-row scale ----------
__global__ __launch_bounds__(256) void quant_k_kernel(
    const float* __restrict__ x, unsigned short* __restrict__ qout,
    float* __restrict__ scl)
{
    const int row  = blockIdx.x * 4 + (threadIdx.x >> 6);
    const int lane = threadIdx.x & 63;
    const float2 v = *(const float2*)(x + (size_t)row * D + lane * 2);
    float m = fmaxf(fabsf(v.x), fabsf(v.y));
    #pragma unroll
    for (int off = 32; off; off >>= 1) m = fmaxf(m, __shfl_xor(m, off));
    const float scale = fmaxf(m / 127.0f, 1e-8f);
    const float q0 = fminf(fmaxf(rintf(v.x / scale), -127.0f), 127.0f);
    const float q1 = fminf(fmaxf(rintf(v.y / scale), -127.0f), 127.0f);
    unsigned int packed = (unsigned int)f2bf(q0) | ((unsigned int)f2bf(q1) << 16);
    *(unsigned int*)(qout + (size_t)row * D + lane * 2) = packed;
    if (lane == 0) scl[row] = scale;
}

// ------------- quantize V: transposed [B,H,D,S] bf16 codes + scale ----------
__global__ __launch_bounds__(256) void quant_v_kernel(
    const float* __restrict__ x, unsigned short* __restrict__ vtq,
    float* __restrict__ scl)
{
    __shared__ __align__(16) unsigned short vt[D][72];
    const int bh = blockIdx.y;
    const int s0 = blockIdx.x * 64;
    const int wave = threadIdx.x >> 6, lane = threadIdx.x & 63;

    #pragma unroll 1
    for (int i = 0; i < 16; i++) {
        const int tok = wave * 16 + i;
        const float2 v = *(const float2*)(x + ((size_t)bh * S + s0 + tok) * D + lane * 2);
        float m = fmaxf(fabsf(v.x), fabsf(v.y));
        #pragma unroll
        for (int off = 32; off; off >>= 1) m = fmaxf(m, __shfl_xor(m, off));
        const float scale = fmaxf(m / 127.0f, 1e-8f);
        const float q0 = fminf(fmaxf(rintf(v.x / scale), -127.0f), 127.0f);
        const float q1 = fminf(fmaxf(rintf(v.y / scale), -127.0f), 127.0f);
        vt[lane * 2    ][tok] = f2bf(q0);
        vt[lane * 2 + 1][tok] = f2bf(q1);
        if (lane == 0) scl[(size_t)bh * S + s0 + tok] = scale;
    }
    __syncthreads();
    const int d = threadIdx.x >> 1, hf = (threadIdx.x & 1) * 32;
    unsigned short* dst = vtq + ((size_t)bh * D + d) * S + s0 + hf;
    #pragma unroll
    for (int i = 0; i < 4; i++)
        *(int4*)(dst + i * 8) = *(const int4*)&vt[d][hf + i * 8];
}

// --------------------------- flash attention --------------------------------
__global__ __launch_bounds__(256) void attn_kernel(
    const float* __restrict__ Q, const unsigned short* __restrict__ Kq,
    const float* __restrict__ Ks, const unsigned short* __restrict__ Vt,
    const float* __restrict__ Vs, float* __restrict__ Out)
{
    __shared__ __align__(16) unsigned short Klds[64][136];
    __shared__ __align__(16) unsigned short Vlds[D][72];
    __shared__ __align__(16) unsigned short Plds[4][16][72];
    __shared__ float KSs[64];
    __shared__ float VSs[64];

    const int bh = blockIdx.y;
    const int qt = blockIdx.x;
    const int tid = threadIdx.x;
    const int wave = tid >> 6, lane = tid & 63;
    const int g = lane >> 4, c = lane & 15;

    // Q fragments: row = c, k-slots = g*8..g*8+7 within each 32-chunk
    bf16x8 qf[4];
    {
        const float* qp = Q + ((size_t)bh * S + qt * 64 + wave * 16 + c) * D + g * 8;
        #pragma unroll
        for (int kk = 0; kk < 4; kk++) {
            float4 a = *(const float4*)(qp + kk * 32);
            float4 b = *(const float4*)(qp + kk * 32 + 4);
            F8 t2;
            t2.u[0] = f2bf(a.x); t2.u[1] = f2bf(a.y); t2.u[2] = f2bf(a.z); t2.u[3] = f2bf(a.w);
            t2.u[4] = f2bf(b.x); t2.u[5] = f2bf(b.y); t2.u[6] = f2bf(b.z); t2.u[7] = f2bf(b.w);
            qf[kk] = t2.b;
        }
    }

    f32x4 acc[8];
    const f32x4 zero = {0.f, 0.f, 0.f, 0.f};
    #pragma unroll
    for (int i = 0; i < 8; i++) acc[i] = zero;
    float mrun[4] = {-1e30f, -1e30f, -1e30f, -1e30f};
    float lrun[4] = {0.f, 0.f, 0.f, 0.f};

    const size_t kbase = (size_t)bh * S * D;

    for (int t = 0; t < S / 64; t++) {
        const int kv0 = t * 64;
        // stage K tile (64 x 128 bf16) into padded LDS
        {
            const int r = tid >> 2, sg = (tid & 3) * 32;
            const unsigned short* src = Kq + kbase + (size_t)(kv0 + r) * D + sg;
            #pragma unroll
            for (int i = 0; i < 4; i++)
                *(int4*)&Klds[r][sg + i * 8] = *(const int4*)(src + i * 8);
        }
        // stage V^T tile (128 x 64 bf16)
        {
            const int d = tid >> 1, hf = (tid & 1) * 32;
            const unsigned short* src = Vt + ((size_t)bh * D + d) * S + kv0 + hf;
            #pragma unroll
            for (int i = 0; i < 4; i++)
                *(int4*)&Vlds[d][hf + i * 8] = *(const int4*)(src + i * 8);
        }
        if (tid < 64)       KSs[tid]      = Ks[(size_t)bh * S + kv0 + tid];
        else if (tid < 128) VSs[tid - 64] = Vs[(size_t)bh * S + kv0 + tid - 64];
        __syncthreads();

        // QK^T: S_tile[16 q][64 kv] per wave
        f32x4 sacc[4];
        #pragma unroll
        for (int n = 0; n < 4; n++) {
            sacc[n] = zero;
            #pragma unroll
            for (int kk = 0; kk < 4; kk++) {
                bf16x8 kf = *(const bf16x8*)&Klds[n * 16 + c][kk * 32 + g * 8];
                sacc[n] = __builtin_amdgcn_mfma_f32_16x16x32_bf16(qf[kk], kf, sacc[n], 0, 0, 0);
            }
        }
        // apply k scales + 1/sqrt(D)
        float sv[4][4];
        #pragma unroll
        for (int n = 0; n < 4; n++) {
            const float kscl = KSs[n * 16 + c] * INV_SQRT_D;
            #pragma unroll
            for (int r = 0; r < 4; r++) sv[n][r] = sacc[n][r] * kscl;
        }
        // online softmax (rows = 4*g + r; cols spread over 16 lanes x 4 n-groups)
        float mnew[4], corr[4];
        #pragma unroll
        for (int r = 0; r < 4; r++) {
            float mx = fmaxf(fmaxf(sv[0][r], sv[1][r]), fmaxf(sv[2][r], sv[3][r]));
            mx = fmaxf(mx, __shfl_xor(mx, 1));
            mx = fmaxf(mx, __shfl_xor(mx, 2));
            mx = fmaxf(mx, __shfl_xor(mx, 4));
            mx = fmaxf(mx, __shfl_xor(mx, 8));
            mnew[r] = fmaxf(mrun[r], mx);
            corr[r] = __expf(mrun[r] - mnew[r]);
            mrun[r] = mnew[r];
        }
        float pv[4][4], psum[4] = {0.f, 0.f, 0.f, 0.f};
        #pragma unroll
        for (int n = 0; n < 4; n++) {
            const float vscl = VSs[n * 16 + c];
            #pragma unroll
            for (int r = 0; r < 4; r++) {
                const float p = __expf(sv[n][r] - mnew[r]);
                psum[r] += p;
                pv[n][r] = p * vscl;   // fold v-scale into P
            }
        }
        #pragma unroll
        for (int r = 0; r < 4; r++) {
            float ps = psum[r];
            ps += __shfl_xor(ps, 1);
            ps += __shfl_xor(ps, 2);
            ps += __shfl_xor(ps, 4);
            ps += __shfl_xor(ps, 8);
            lrun[r] = lrun[r] * corr[r] + ps;
        }
        #pragma unroll
        for (int nd = 0; nd < 8; nd++) {
            #pragma unroll
            for (int r = 0; r < 4; r++) acc[nd][r] *= corr[r];
        }
        // write P' (bf16) to wave-private LDS, indexed by true kv
        #pragma unroll
        for (int n = 0; n < 4; n++) {
            #pragma unroll
            for (int r = 0; r < 4; r++)
                Plds[wave][4 * g + r][n * 16 + c] = f2bf(pv[n][r]);
        }
        // PV: O[16 q][128 d] += P'[16 x 64] * Vint[64 x 128]
        bf16x8 pf[2];
        #pragma unroll
        for (int kk = 0; kk < 2; kk++)
            pf[kk] = *(const bf16x8*)&Plds[wave][c][kk * 32 + g * 8];
        #pragma unroll
        for (int nd = 0; nd < 8; nd++) {
            #pragma unroll
            for (int kk = 0; kk < 2; kk++) {
                bf16x8 vf = *(const bf16x8*)&Vlds[nd * 16 + c][kk * 32 + g * 8];
                acc[nd] = __builtin_amdgcn_mfma_f32_16x16x32_bf16(pf[kk], vf, acc[nd], 0, 0, 0);
            }
        }
        __syncthreads();
    }

    // epilogue: divide by softmax denom, store f32
    #pragma unroll
    for (int r = 0; r < 4; r++) {
        const float inv = 1.0f / lrun[r];
        const size_t orow = ((size_t)bh * S + qt * 64 + wave * 16 + 4 * g + r) * (size_t)D;
        #pragma unroll
        for (int nd = 0; nd < 8; nd++)
            Out[orow + nd * 16 + c] = acc[nd][r] * inv;
    }
}

extern "C" void kernel_launch(void* const* d_in, const int* in_sizes, int n_in,
                              void* d_out, int out_size, void* d_ws, size_t ws_size,
                              hipStream_t stream) {
    const float* q = (const float*)d_in[0];
    const float* k = (const float*)d_in[1];
    const float* v = (const float*)d_in[2];
    float* out = (float*)d_out;

    const size_t ELEMS = (size_t)NROWS * D; // 16777216
    unsigned short* kq  = (unsigned short*)d_ws;
    unsigned short* vtq = kq + ELEMS;
    float* ks = (float*)(vtq + ELEMS);
    float* vs = ks + NROWS;

    quant_k_kernel<<<NROWS / 4, 256, 0, stream>>>(k, kq, ks);
    quant_v_kernel<<<dim3(S / 64, B * H), 256, 0, stream>>>(v, vtq, vs);
    attn_kernel<<<dim3(S / 64, B * H), 256, 0, stream>>>(q, kq, ks, vtq, vs, out);
}

// Round 2
// 353.704 us; speedup vs baseline: 1.1196x; 1.1196x over previous
//
#include <hip/hip_runtime.h>
#include <hip/hip_bf16.h>

#define B 2
#define H 32
#define S 2048
#define D 128

typedef __bf16 bf16x8 __attribute__((ext_vector_type(8)));
typedef float f32x4 __attribute__((ext_vector_type(4)));

union BF8U { unsigned int u[4]; unsigned short s[8]; bf16x8 b; };

static constexpr float INV_SQRT_D = 0.08838834764831845f; // 1/sqrt(128)
static constexpr int NROWS = B * H * S; // 131072

__device__ __forceinline__ unsigned short bfbits(float f) {
    union { __bf16 h; unsigned short s; } cv;
    cv.h = (__bf16)f;  // native cvt (RNE); exact for small ints
    return cv.s;
}
__device__ __forceinline__ unsigned int pack2bf(float a, float b) {
    union { unsigned short s[2]; unsigned int u; } cv;
    cv.s[0] = bfbits(a); cv.s[1] = bfbits(b);
    return cv.u;
}

// ---------------- quantize K: row-major bf16 codes + per-row scale*1/sqrt(D)
__global__ __launch_bounds__(256) void quant_k_kernel(
    const float* __restrict__ x, unsigned short* __restrict__ qout,
    float* __restrict__ scl)
{
    const int row  = blockIdx.x * 4 + (threadIdx.x >> 6);
    const int lane = threadIdx.x & 63;
    const float2 v = *(const float2*)(x + (size_t)row * D + lane * 2);
    float m = fmaxf(fabsf(v.x), fabsf(v.y));
    #pragma unroll
    for (int off = 32; off; off >>= 1) m = fmaxf(m, __shfl_xor(m, off));
    const float scale = fmaxf(m / 127.0f, 1e-8f);
    const float q0 = fminf(fmaxf(rintf(v.x / scale), -127.0f), 127.0f);
    const float q1 = fminf(fmaxf(rintf(v.y / scale), -127.0f), 127.0f);
    *(unsigned int*)(qout + (size_t)row * D + lane * 2) = pack2bf(q0, q1);
    if (lane == 0) scl[row] = scale * INV_SQRT_D;
}

// ------------- quantize V: transposed [B,H,D,S] bf16 codes + scale ----------
__global__ __launch_bounds__(256) void quant_v_kernel(
    const float* __restrict__ x, unsigned short* __restrict__ vtq,
    float* __restrict__ scl)
{
    __shared__ __align__(16) unsigned short vt[D][72];
    const int bh = blockIdx.y;
    const int s0 = blockIdx.x * 64;
    const int wave = threadIdx.x >> 6, lane = threadIdx.x & 63;

    #pragma unroll 1
    for (int i = 0; i < 16; i++) {
        const int tok = wave * 16 + i;
        const float2 v = *(const float2*)(x + ((size_t)bh * S + s0 + tok) * D + lane * 2);
        float m = fmaxf(fabsf(v.x), fabsf(v.y));
        #pragma unroll
        for (int off = 32; off; off >>= 1) m = fmaxf(m, __shfl_xor(m, off));
        const float scale = fmaxf(m / 127.0f, 1e-8f);
        const float q0 = fminf(fmaxf(rintf(v.x / scale), -127.0f), 127.0f);
        const float q1 = fminf(fmaxf(rintf(v.y / scale), -127.0f), 127.0f);
        vt[lane * 2    ][tok] = bfbits(q0);
        vt[lane * 2 + 1][tok] = bfbits(q1);
        if (lane == 0) scl[(size_t)bh * S + s0 + tok] = scale;
    }
    __syncthreads();
    const int d = threadIdx.x >> 1, hf = (threadIdx.x & 1) * 32;
    unsigned short* dst = vtq + ((size_t)bh * D + d) * S + s0 + hf;
    #pragma unroll
    for (int i = 0; i < 4; i++)
        *(int4*)(dst + i * 8) = *(const int4*)&vt[d][hf + i * 8];
}

// --------------------------- flash attention --------------------------------
// Swapped QK^T: S[kv][q] with q = lane&15 lane-local -> in-register softmax.
__global__ __launch_bounds__(256, 4) void attn_kernel(
    const float* __restrict__ Q, const unsigned short* __restrict__ Kq,
    const float* __restrict__ Ks, const unsigned short* __restrict__ Vt,
    const float* __restrict__ Vs, float* __restrict__ Out)
{
    __shared__ __align__(16) unsigned short Klds[64][136];
    __shared__ __align__(16) unsigned short Vlds[D][72];
    __shared__ float KSs[64];
    __shared__ float VSs[64];

    const int bh = blockIdx.y;
    const int qt = blockIdx.x;
    const int tid = threadIdx.x;
    const int wave = tid >> 6, lane = tid & 63;
    const int g = lane >> 4, c = lane & 15;

    // Q fragments (B operand): lane holds Q[q=c][k=g*8.. within each 32-chunk]
    bf16x8 qf[4];
    {
        const float* qp = Q + ((size_t)bh * S + qt * 64 + wave * 16 + c) * D + g * 8;
        #pragma unroll
        for (int kk = 0; kk < 4; kk++) {
            float4 a = *(const float4*)(qp + kk * 32);
            float4 b = *(const float4*)(qp + kk * 32 + 4);
            BF8U t;
            t.s[0] = bfbits(a.x); t.s[1] = bfbits(a.y); t.s[2] = bfbits(a.z); t.s[3] = bfbits(a.w);
            t.s[4] = bfbits(b.x); t.s[5] = bfbits(b.y); t.s[6] = bfbits(b.z); t.s[7] = bfbits(b.w);
            qf[kk] = t.b;
        }
    }

    f32x4 acc[8];
    const f32x4 zero = {0.f, 0.f, 0.f, 0.f};
    #pragma unroll
    for (int i = 0; i < 8; i++) acc[i] = zero;
    float mrun = -1e30f, lrun = 0.f;   // per-lane scalars, q = c (replicated x4 over g)

    const size_t kbase = (size_t)bh * S * D;

    for (int t = 0; t < S / 64; t++) {
        const int kv0 = t * 64;
        // stage K tile (64 x 128 bf16)
        {
            const int r = tid >> 2, sg = (tid & 3) * 32;
            const unsigned short* src = Kq + kbase + (size_t)(kv0 + r) * D + sg;
            #pragma unroll
            for (int i = 0; i < 4; i++)
                *(int4*)&Klds[r][sg + i * 8] = *(const int4*)(src + i * 8);
        }
        // stage V^T tile (128 x 64 bf16)
        {
            const int d = tid >> 1, hf = (tid & 1) * 32;
            const unsigned short* src = Vt + ((size_t)bh * D + d) * S + kv0 + hf;
            #pragma unroll
            for (int i = 0; i < 4; i++)
                *(int4*)&Vlds[d][hf + i * 8] = *(const int4*)(src + i * 8);
        }
        if (tid < 64)       KSs[tid]      = Ks[(size_t)bh * S + kv0 + tid];
        else if (tid < 128) VSs[tid - 64] = Vs[(size_t)bh * S + kv0 + tid - 64];
        __syncthreads();

        // QK^T swapped: sacc[n] reg r at lane (g,c) = S[kv=16n+4g+r][q=c]
        f32x4 sacc[4];
        #pragma unroll
        for (int n = 0; n < 4; n++) {
            sacc[n] = zero;
            #pragma unroll
            for (int kk = 0; kk < 4; kk++) {
                bf16x8 kf = *(const bf16x8*)&Klds[n * 16 + c][kk * 32 + g * 8];
                sacc[n] = __builtin_amdgcn_mfma_f32_16x16x32_bf16(kf, qf[kk], sacc[n], 0, 0, 0);
            }
        }
        // scales: broadcast f32x4 (same addr for all 16 c-lanes)
        f32x4 ksv[4], vsv[4];
        #pragma unroll
        for (int n = 0; n < 4; n++) {
            ksv[n] = *(const f32x4*)&KSs[n * 16 + 4 * g];
            vsv[n] = *(const f32x4*)&VSs[n * 16 + 4 * g];
        }
        float sv[4][4];
        float mx = -1e30f;
        #pragma unroll
        for (int n = 0; n < 4; n++)
            #pragma unroll
            for (int r = 0; r < 4; r++) {
                sv[n][r] = sacc[n][r] * ksv[n][r];
                mx = fmaxf(mx, sv[n][r]);
            }
        mx = fmaxf(mx, __shfl_xor(mx, 16));
        mx = fmaxf(mx, __shfl_xor(mx, 32));
        const float mnew = fmaxf(mrun, mx);
        const float corr = __expf(mrun - mnew);
        mrun = mnew;

        float ps = 0.f;
        float pv[4][4];
        #pragma unroll
        for (int n = 0; n < 4; n++)
            #pragma unroll
            for (int r = 0; r < 4; r++) {
                const float p = __expf(sv[n][r] - mnew);
                ps += p;
                pv[n][r] = p * vsv[n][r];   // fold v-scale into P
            }
        ps += __shfl_xor(ps, 16);
        ps += __shfl_xor(ps, 32);
        lrun = lrun * corr + ps;

        // rescale acc rows (acc row index = q = 4g+r; corr lives at lane q)
        float corr_q[4];
        #pragma unroll
        for (int r = 0; r < 4; r++) corr_q[r] = __shfl(corr, 4 * g + r);
        #pragma unroll
        for (int nd = 0; nd < 8; nd++)
            #pragma unroll
            for (int r = 0; r < 4; r++) acc[nd][r] *= corr_q[r];

        // pack P' to bf16 pairs: w[n][r2] = kv pair {16n+4g+2r2, +1} at q=c
        unsigned int w[4][2];
        #pragma unroll
        for (int n = 0; n < 4; n++) {
            w[n][0] = pack2bf(pv[n][0], pv[n][1]);
            w[n][1] = pack2bf(pv[n][2], pv[n][3]);
        }
        // redistribute: pf[kk] word j (kv = kk*32+8g+2j) comes from
        // lane (c + 16*(2(g&1)+(j>>1))), word w[2kk+(g>>1)][j&1]
        const int srcA = c + 32 * (g & 1);
        unsigned int pw[2][4];
        #pragma unroll
        for (int kk = 0; kk < 2; kk++)
            #pragma unroll
            for (int j = 0; j < 4; j++) {
                const int src = srcA + ((j >> 1) << 4);
                const int vA = __shfl((int)w[2 * kk + 0][j & 1], src);
                const int vB = __shfl((int)w[2 * kk + 1][j & 1], src);
                pw[kk][j] = (unsigned int)((g & 2) ? vB : vA);
            }
        bf16x8 pf[2];
        #pragma unroll
        for (int kk = 0; kk < 2; kk++) {
            BF8U t;
            t.u[0] = pw[kk][0]; t.u[1] = pw[kk][1];
            t.u[2] = pw[kk][2]; t.u[3] = pw[kk][3];
            pf[kk] = t.b;
        }
        // PV: O[q=4g+r][d=nd*16+c] accumulate
        #pragma unroll
        for (int nd = 0; nd < 8; nd++)
            #pragma unroll
            for (int kk = 0; kk < 2; kk++) {
                bf16x8 vf = *(const bf16x8*)&Vlds[nd * 16 + c][kk * 32 + g * 8];
                acc[nd] = __builtin_amdgcn_mfma_f32_16x16x32_bf16(pf[kk], vf, acc[nd], 0, 0, 0);
            }
        __syncthreads();
    }

    // epilogue
    const float inv = 1.0f / lrun;
    float inv_q[4];
    #pragma unroll
    for (int r = 0; r < 4; r++) inv_q[r] = __shfl(inv, 4 * g + r);
    #pragma unroll
    for (int r = 0; r < 4; r++) {
        const size_t orow = ((size_t)bh * S + qt * 64 + wave * 16 + 4 * g + r) * (size_t)D;
        #pragma unroll
        for (int nd = 0; nd < 8; nd++)
            Out[orow + nd * 16 + c] = acc[nd][r] * inv_q[r];
    }
}

extern "C" void kernel_launch(void* const* d_in, const int* in_sizes, int n_in,
                              void* d_out, int out_size, void* d_ws, size_t ws_size,
                              hipStream_t stream) {
    const float* q = (const float*)d_in[0];
    const float* k = (const float*)d_in[1];
    const float* v = (const float*)d_in[2];
    float* out = (float*)d_out;

    const size_t ELEMS = (size_t)NROWS * D; // 16777216
    unsigned short* kq  = (unsigned short*)d_ws;
    unsigned short* vtq = kq + ELEMS;
    float* ks = (float*)(vtq + ELEMS);
    float* vs = ks + NROWS;

    quant_k_kernel<<<NROWS / 4, 256, 0, stream>>>(k, kq, ks);
    quant_v_kernel<<<dim3(S / 64, B * H), 256, 0, stream>>>(v, vtq, vs);
    attn_kernel<<<dim3(S / 64, B * H), 256, 0, stream>>>(q, kq, ks, vtq, vs, out);
}